// Round 9
// baseline (277.489 us; speedup 1.0000x reference)
//
#include <hip/hip_runtime.h>
#include <math.h>

#define NB     32
#define FH     11
#define FW     20
#define CIN    512
#define CMID   1024
#define NANG   17
#define NPREDD 77
#define NEDGE  42
#define NPROPP 714
#define NOFF   72
#define NCLS   34
#define NREGR  1241
#define N2PAD  1280
#define MTOT   1344      // NB * NEDGE
#define NSTRIPSF 71.0f
#define PADK   40        // padded LDS row length in bf16 units (conflict-free b128)

typedef unsigned long long u64;
typedef unsigned short ushortt;
typedef short s8v __attribute__((ext_vector_type(8)));
typedef float f4v __attribute__((ext_vector_type(4)));

__device__ inline ushortt f2bf(float f) {          // RNE fp32 -> bf16
    unsigned u = __float_as_uint(f);
    u += 0x7fffu + ((u >> 16) & 1u);
    return (ushortt)(u >> 16);
}
__device__ inline float bf2f(ushortt h) {
    return __uint_as_float(((unsigned)h) << 16);
}

// ------------- gather edge pixels + split to hi/lo bf16: A1[m][c] -------------
__global__ __launch_bounds__(256) void k_gather_split(const float* __restrict__ feat,
                                                      ushortt* __restrict__ Ahi,
                                                      ushortt* __restrict__ Alo)
{
    int idx = blockIdx.x * 256 + threadIdx.x;    // exactly MTOT*CIN = 688128
    int m = idx >> 9, c = idx & 511;
    int b = m / NEDGE, e = m - b * NEDGE;
    int h, w;
    if (e < FH)          { h = e;      w = 0;      }
    else if (e < 2 * FH) { h = e - FH; w = FW - 1; }
    else                 { h = FH - 1; w = e - 2 * FH; }
    float v = feat[((size_t)(b * CIN + c) * FH + h) * FW + w];
    ushortt hi = f2bf(v);
    Ahi[idx] = hi;
    Alo[idx] = f2bf(v - bf2f(hi));
}

// ------------- GEMM1 (MFMA): [1344][1024] = A1 x Wconv^T + bconv, out hi/lo bf16 ---
__global__ __launch_bounds__(256) void k_gemm1m(const ushortt* __restrict__ Ahi,
                                                const ushortt* __restrict__ Alo,
                                                const float* __restrict__ W,
                                                const float* __restrict__ bias,
                                                ushortt* __restrict__ Chi,
                                                ushortt* __restrict__ Clo)
{
    const int K = CIN, N = CMID;
    __shared__ __align__(16) ushortt Ash[64 * PADK], Asl[64 * PADK];
    __shared__ __align__(16) ushortt Bsh[64 * PADK], Bsl[64 * PADK];
    int tid = threadIdx.x;
    int m0 = blockIdx.y * 64, n0 = blockIdx.x * 64;
    int srow = tid >> 2, sg = tid & 3;
    int lane = tid & 63, wv = tid >> 6;
    int wm = (wv & 1) * 32, wn = (wv >> 1) * 32;
    int quad = lane >> 4, l15 = lane & 15;

    f4v acc[2][2];
#pragma unroll
    for (int i = 0; i < 2; ++i)
#pragma unroll
        for (int j = 0; j < 2; ++j) acc[i][j] = (f4v){0.f, 0.f, 0.f, 0.f};

    const ushortt* Ahp = Ahi + (size_t)(m0 + srow) * K + sg * 8;
    const ushortt* Alp = Alo + (size_t)(m0 + srow) * K + sg * 8;
    const float*   Wp  = W   + (size_t)(n0 + srow) * K + sg * 8;

    for (int k0 = 0; k0 < K; k0 += 32) {
        __syncthreads();
        s8v av = *(const s8v*)(Ahp + k0);
        s8v lv = *(const s8v*)(Alp + k0);
        float4 w0 = *(const float4*)(Wp + k0);
        float4 w1 = *(const float4*)(Wp + k0 + 4);
        float wf[8] = {w0.x, w0.y, w0.z, w0.w, w1.x, w1.y, w1.z, w1.w};
        s8v wh, wl;
#pragma unroll
        for (int j = 0; j < 8; ++j) {
            ushortt h = f2bf(wf[j]);
            wh[j] = (short)h;
            wl[j] = (short)f2bf(wf[j] - bf2f(h));
        }
        *(s8v*)&Ash[srow * PADK + sg * 8] = av;
        *(s8v*)&Asl[srow * PADK + sg * 8] = lv;
        *(s8v*)&Bsh[srow * PADK + sg * 8] = wh;
        *(s8v*)&Bsl[srow * PADK + sg * 8] = wl;
        __syncthreads();
        s8v ah[2], al[2], bh[2], bl[2];
#pragma unroll
        for (int s = 0; s < 2; ++s) {
            ah[s] = *(const s8v*)&Ash[(wm + s * 16 + l15) * PADK + quad * 8];
            al[s] = *(const s8v*)&Asl[(wm + s * 16 + l15) * PADK + quad * 8];
            bh[s] = *(const s8v*)&Bsh[(wn + s * 16 + l15) * PADK + quad * 8];
            bl[s] = *(const s8v*)&Bsl[(wn + s * 16 + l15) * PADK + quad * 8];
        }
#pragma unroll
        for (int sm = 0; sm < 2; ++sm)
#pragma unroll
            for (int sn = 0; sn < 2; ++sn) {
                acc[sm][sn] = __builtin_amdgcn_mfma_f32_16x16x32_bf16(al[sm], bl[sn], acc[sm][sn], 0, 0, 0);
                acc[sm][sn] = __builtin_amdgcn_mfma_f32_16x16x32_bf16(al[sm], bh[sn], acc[sm][sn], 0, 0, 0);
                acc[sm][sn] = __builtin_amdgcn_mfma_f32_16x16x32_bf16(ah[sm], bl[sn], acc[sm][sn], 0, 0, 0);
                acc[sm][sn] = __builtin_amdgcn_mfma_f32_16x16x32_bf16(ah[sm], bh[sn], acc[sm][sn], 0, 0, 0);
            }
    }
#pragma unroll
    for (int sm = 0; sm < 2; ++sm)
#pragma unroll
        for (int sn = 0; sn < 2; ++sn)
#pragma unroll
            for (int r = 0; r < 4; ++r) {
                int m = m0 + wm + sm * 16 + quad * 4 + r;
                int n = n0 + wn + sn * 16 + l15;
                float v = acc[sm][sn][r] + bias[n];
                ushortt h = f2bf(v);
                Chi[(size_t)m * N + n] = h;
                Clo[(size_t)m * N + n] = f2bf(v - bf2f(h));
            }
}

// ------------- GEMM2 (MFMA): C2[1344][1280] = A2 x [Wcls;Wreg;0]^T + bias, fp32 out ---
__global__ __launch_bounds__(256) void k_gemm2m(const ushortt* __restrict__ Ahi,
                                                const ushortt* __restrict__ Alo,
                                                const float* __restrict__ Wcls,
                                                const float* __restrict__ bcls,
                                                const float* __restrict__ Wreg,
                                                const float* __restrict__ breg,
                                                float* __restrict__ C)
{
    const int K = CMID;
    __shared__ __align__(16) ushortt Ash[64 * PADK], Asl[64 * PADK];
    __shared__ __align__(16) ushortt Bsh[64 * PADK], Bsl[64 * PADK];
    int tid = threadIdx.x;
    int m0 = blockIdx.y * 64, n0 = blockIdx.x * 64;
    int srow = tid >> 2, sg = tid & 3;
    int lane = tid & 63, wv = tid >> 6;
    int wm = (wv & 1) * 32, wn = (wv >> 1) * 32;
    int quad = lane >> 4, l15 = lane & 15;

    f4v acc[2][2];
#pragma unroll
    for (int i = 0; i < 2; ++i)
#pragma unroll
        for (int j = 0; j < 2; ++j) acc[i][j] = (f4v){0.f, 0.f, 0.f, 0.f};

    const ushortt* Ahp = Ahi + (size_t)(m0 + srow) * K + sg * 8;
    const ushortt* Alp = Alo + (size_t)(m0 + srow) * K + sg * 8;
    int nrow = n0 + srow;
    const float* Wp = Wcls;
    bool wvalid = true;
    if (nrow < NCLS)              Wp = Wcls + (size_t)nrow * K + sg * 8;
    else if (nrow < NCLS + NREGR) Wp = Wreg + (size_t)(nrow - NCLS) * K + sg * 8;
    else                          wvalid = false;

    for (int k0 = 0; k0 < K; k0 += 32) {
        __syncthreads();
        s8v av = *(const s8v*)(Ahp + k0);
        s8v lv = *(const s8v*)(Alp + k0);
        float4 w0, w1;
        if (wvalid) {
            w0 = *(const float4*)(Wp + k0);
            w1 = *(const float4*)(Wp + k0 + 4);
        } else {
            w0 = make_float4(0.f, 0.f, 0.f, 0.f);
            w1 = w0;
        }
        float wf[8] = {w0.x, w0.y, w0.z, w0.w, w1.x, w1.y, w1.z, w1.w};
        s8v wh, wl;
#pragma unroll
        for (int j = 0; j < 8; ++j) {
            ushortt h = f2bf(wf[j]);
            wh[j] = (short)h;
            wl[j] = (short)f2bf(wf[j] - bf2f(h));
        }
        *(s8v*)&Ash[srow * PADK + sg * 8] = av;
        *(s8v*)&Asl[srow * PADK + sg * 8] = lv;
        *(s8v*)&Bsh[srow * PADK + sg * 8] = wh;
        *(s8v*)&Bsl[srow * PADK + sg * 8] = wl;
        __syncthreads();
        s8v ah[2], al[2], bh[2], bl[2];
#pragma unroll
        for (int s = 0; s < 2; ++s) {
            ah[s] = *(const s8v*)&Ash[(wm + s * 16 + l15) * PADK + quad * 8];
            al[s] = *(const s8v*)&Asl[(wm + s * 16 + l15) * PADK + quad * 8];
            bh[s] = *(const s8v*)&Bsh[(wn + s * 16 + l15) * PADK + quad * 8];
            bl[s] = *(const s8v*)&Bsl[(wn + s * 16 + l15) * PADK + quad * 8];
        }
#pragma unroll
        for (int sm = 0; sm < 2; ++sm)
#pragma unroll
            for (int sn = 0; sn < 2; ++sn) {
                acc[sm][sn] = __builtin_amdgcn_mfma_f32_16x16x32_bf16(al[sm], bl[sn], acc[sm][sn], 0, 0, 0);
                acc[sm][sn] = __builtin_amdgcn_mfma_f32_16x16x32_bf16(al[sm], bh[sn], acc[sm][sn], 0, 0, 0);
                acc[sm][sn] = __builtin_amdgcn_mfma_f32_16x16x32_bf16(ah[sm], bl[sn], acc[sm][sn], 0, 0, 0);
                acc[sm][sn] = __builtin_amdgcn_mfma_f32_16x16x32_bf16(ah[sm], bh[sn], acc[sm][sn], 0, 0, 0);
            }
    }
#pragma unroll
    for (int sm = 0; sm < 2; ++sm)
#pragma unroll
        for (int sn = 0; sn < 2; ++sn)
#pragma unroll
            for (int r = 0; r < 4; ++r) {
                int m = m0 + wm + sm * 16 + quad * 4 + r;
                int n = n0 + wn + sn * 16 + l15;
                float bb = (n < NCLS) ? bcls[n] : ((n < NCLS + NREGR) ? breg[n - NCLS] : 0.f);
                C[(size_t)m * N2PAD + n] = acc[sm][sn][r] + bb;
            }
}

// ---------------- assemble proposals + scores + start/end + xsel ----------------
__global__ __launch_bounds__(256) void k_assemble(const float* __restrict__ C2,
                                                  const float* __restrict__ AD,
                                                  float* __restrict__ outP,
                                                  float* __restrict__ outS,
                                                  float* __restrict__ startv,
                                                  float* __restrict__ endv,
                                                  float* __restrict__ xsel)
{
    int mb = blockIdx.x;                 // 0..1343
    int b = mb / NEDGE, e = mb - b * NEDGE;
    const float* c2 = C2 + (size_t)mb * N2PAD;
    int tid = threadIdx.x;
    for (int idx = tid; idx < NANG * NPREDD; idx += 256) {
        int a = idx / NPREDD, p = idx - a * NPREDD;
        int prop = e * NANG + a;
        float v;
        if (p < 2) v = c2[a * 2 + p];
        else {
            v = AD[prop * NPREDD + p];
            if (p >= 4) v += c2[NCLS + a * 73 + (p - 4)];
        }
        outP[((size_t)b * NPROPP + prop) * NPREDD + p] = v;
    }
    if (tid < NANG) {
        int a = tid, prop = e * NANG + a;
        float c0 = c2[2 * a], c1 = c2[2 * a + 1];
        float mx = fmaxf(c0, c1);
        float e0 = expf(c0 - mx), e1 = expf(c1 - mx);
        outS[b * NPROPP + prop] = e1 / (e0 + e1);
        float p2 = AD[prop * NPREDD + 2];
        float p4 = AD[prop * NPREDD + 4] + c2[NCLS + a * 73];
        float st = fminf(fmaxf(rintf(p2 * NSTRIPSF), 0.0f), NSTRIPSF);  // round half-to-even
        float en = fminf(fmaxf(st + p4 - 1.0f, 0.0f), NSTRIPSF);
        startv[b * 720 + prop] = st;
        endv[b * 720 + prop] = en;
        int ksi = (int)st;
        // bit-identical to outP[..][5+ksi]
        xsel[b * 720 + prop] = AD[prop * NPREDD + 5 + ksi] + c2[NCLS + a * 73 + ksi + 1];
    }
}

// ---------------- per-batch stable descending rank sort ----------------
__global__ __launch_bounds__(256) void k_sort(const float* __restrict__ scores,
                                              int* __restrict__ order)
{
    int b = blockIdx.x, tid = threadIdx.x;
    __shared__ float s[NPROPP];
    for (int i = tid; i < NPROPP; i += 256) s[i] = scores[b * NPROPP + i];
    __syncthreads();
    for (int i = tid; i < NPROPP; i += 256) {
        float si = s[i];
        int r = 0;
        for (int j = 0; j < NPROPP; ++j) {
            float sj = s[j];
            r += (sj > si) || (sj == si && j < i);
        }
        order[b * 720 + r] = i;
    }
}

// ---------------- suppression matrix, 64x64 tiles, xsel fast path ----------------
__global__ __launch_bounds__(256) void k_supmat(const float* __restrict__ outP,
                                                const float* __restrict__ startv,
                                                const float* __restrict__ endv,
                                                const float* __restrict__ xsel,
                                                const int* __restrict__ order,
                                                u64* __restrict__ sup)
{
    int jt = blockIdx.x, it = blockIdx.y, b = blockIdx.z;
    int i0 = it * 64, j0 = jt * 64;
    int tid = threadIdx.x;
    if (j0 + 63 < i0) {                  // strictly below diagonal: zero words
        if (tid < 64) {
            int il = i0 + tid;
            if (il < NPROPP) sup[((size_t)b * NPROPP + il) * 12 + jt] = 0ull;
        }
        return;
    }
    __shared__ float SI[64], EI[64], XI[64];
    __shared__ float SJ[64], EJ[64], XJ[64];
    __shared__ int   OI[64], OJ[64];
    if (tid < 128) {
        int side = tid >> 6, q = tid & 63;
        int pos = (side ? j0 : i0) + q;
        int o = (pos < NPROPP) ? order[b * 720 + pos] : -1;
        float st = (o >= 0) ? startv[b * 720 + o] : 0.f;
        float en = (o >= 0) ? endv[b * 720 + o] : -2.f;   // cnt<=-1 -> never suppress
        float xv = (o >= 0) ? xsel[b * 720 + o] : 0.f;
        if (!side) { SI[q] = st; EI[q] = en; XI[q] = xv; OI[q] = o; }
        else       { SJ[q] = st; EJ[q] = en; XJ[q] = xv; OJ[q] = o; }
    }
    __syncthreads();
    int lane = tid & 63, w = tid >> 6;
    int j = j0 + lane;
    float sj = SJ[lane], ej = EJ[lane], xj = XJ[lane];
    const float* basexs = outP + (size_t)b * NPROPP * NPREDD + 5;
#pragma unroll 1
    for (int rep = 0; rep < 16; ++rep) {
        int iloc = w * 16 + rep;
        int il = i0 + iloc;
        float si = SI[iloc], ei = EI[iloc];
        float s = fmaxf(si, sj), e = fminf(ei, ej);
        float cnt = e - s + 1.0f;
        bool sp = false;
        if (cnt > 0.f) {
            if (e < s) {
                sp = true;                               // empty range: dist = 0
            } else {
                int ks = (int)s, ke = (int)e;
                if (si == sj && ke == ks) {
                    sp = (fabsf(XI[iloc] - xj) / fmaxf(cnt, 1.0f)) < 15.0f;
                } else {                                  // rare general case
                    const float* xi  = basexs + (size_t)OI[iloc] * NPREDD;
                    const float* xjp = basexs + (size_t)OJ[lane] * NPREDD;
                    float sum = 0.f;
                    for (int k = ks; k <= ke; ++k)
                        sum += fabsf(xi[k] - xjp[k]);
                    sp = (sum / fmaxf(cnt, 1.0f)) < 15.0f;
                }
            }
        }
        bool valid = (il < NPROPP) && (j < NPROPP) && (j > il);
        u64 msk = __ballot(valid && sp);
        if (lane == 0 && il < NPROPP)
            sup[((size_t)b * NPROPP + il) * 12 + jt] = msk;
    }
}

// ---------------- sequential NMS scan (per batch, 1 wave) ----------------
// Set-bit iteration: sequential steps only for KEPT rows (~40-80 of 714).
//   alive = ~S0 & valid; pending = alive;
//   i = ctz(pending); keep i; alive &= ~row_i (row has only j>i bits);
//   pending = alive & bits>i.
// Suppressed rows are skipped entirely (they contribute nothing - exact
// reference semantics). Cross-chunk state: kept lanes ds_or their (shifted)
// future words into SUPW[]; next chunk reads SUPW[c] as uniform S0 (single
// wave -> program order + compiler lgkmcnt makes this safe).
__global__ __launch_bounds__(64) void k_scan(const u64* __restrict__ sup,
                                             const int* __restrict__ order,
                                             float* __restrict__ keep_out)
{
    int b = blockIdx.x, lane = threadIdx.x;
    __shared__ float keepv[NPROPP];
    __shared__ int ord[NPROPP];
    __shared__ u64 SUPW[12];
    for (int x = lane; x < NPROPP; x += 64) { keepv[x] = 0.f; ord[x] = order[b * 720 + x]; }
    if (lane < 12) SUPW[lane] = 0ull;
    __syncthreads();
    const u64* base = sup + (size_t)b * NPROPP * 12;

    u64 cur[12], nxt[12];
    {   // chunk 0, shifted: cur[t] = word t of sorted row `lane`
        int r = lane;
#pragma unroll
        for (int t = 0; t < 12; ++t)
            cur[t] = (r < NPROPP) ? base[(size_t)r * 12 + t] : 0ull;
    }

#pragma unroll 1
    for (int c = 0; c < 12; ++c) {
        if (c < 11) {       // prefetch next chunk, shifted by (c+1)
            int r = (c + 1) * 64 + lane;
#pragma unroll
            for (int t = 0; t < 12; ++t) {
                int w = c + 1 + t;
                nxt[t] = (r < NPROPP && w < 12) ? base[(size_t)r * 12 + w] : 0ull;
            }
        }
        int imax = NPROPP - c * 64; if (imax > 64) imax = 64;
        u64 vmask = (imax >= 64) ? ~0ull : ((1ull << imax) - 1ull);
        u64 S0 = SUPW[c];                  // waits on prior chunks' ds_or
        u64 alive = ~S0 & vmask;
        u64 keepbits = 0ull;
        u64 pending = alive;
        while (pending) {
            int i = (int)__builtin_ctzll(pending);
            keepbits |= (1ull << i);
            unsigned rlo = (unsigned)__builtin_amdgcn_readlane((int)(unsigned)cur[0], i);
            unsigned rhi = (unsigned)__builtin_amdgcn_readlane((int)(cur[0] >> 32), i);
            u64 row = ((u64)rhi << 32) | (u64)rlo;   // only bits > i are set
            alive &= ~row;
            u64 hm = (~0ull << i) << 1;              // bits strictly above i
            pending = alive & hm;
        }
        if (lane < imax)
            keepv[ord[c * 64 + lane]] = ((keepbits >> lane) & 1ull) ? 1.f : 0.f;
        if ((keepbits >> lane) & 1ull) {             // kept lanes push future words
#pragma unroll
            for (int t = 1; t < 12; ++t)
                if (c + t < 12)
                    atomicOr(&SUPW[c + t], cur[t]);
        }
#pragma unroll
        for (int t = 0; t < 12; ++t) cur[t] = nxt[t];
    }
    __syncthreads();
    for (int x = lane; x < NPROPP; x += 64) keep_out[b * NPROPP + x] = keepv[x];
}

extern "C" void kernel_launch(void* const* d_in, const int* in_sizes, int n_in,
                              void* d_out, int out_size, void* d_ws, size_t ws_size,
                              hipStream_t stream)
{
    const float* feat  = (const float*)d_in[0];
    const float* Wconv = (const float*)d_in[1];
    const float* bconv = (const float*)d_in[2];
    const float* Wcls  = (const float*)d_in[3];
    const float* bcls  = (const float*)d_in[4];
    const float* Wreg  = (const float*)d_in[5];
    const float* breg  = (const float*)d_in[6];
    const float* AD    = (const float*)d_in[8];   // anchors_anchor_dim (714,77)

    float* out  = (float*)d_out;
    float* outP = out;                                     // proposals 32*714*77
    float* outK = out + (size_t)NB * NPROPP * NPREDD;      // keep mask  32*714
    float* outS = outK + (size_t)NB * NPROPP;              // scores     32*714

    float* ws = (float*)d_ws;
    // [0, 688128) floats: A1hi/A1lo bf16 (dead after gemm1) -> NMS scratch later
    ushortt* A1hi = (ushortt*)ws;                          // 688128 bf16
    ushortt* A1lo = (ushortt*)(ws + 344064);               // 688128 bf16
    ushortt* A2hi = (ushortt*)(ws + 688128);               // 1344*1024 bf16
    ushortt* A2lo = (ushortt*)(ws + 1376256);              // 1344*1024 bf16
    float*   C2   = ws + 2064384;                          // 1344*1280 fp32, ends 3784704
    // NMS scratch overlays dead A1 region:
    float* startv = ws;                                    // 32*720 floats
    float* endv   = ws + 23040;                            // 32*720 floats
    int*   order  = (int*)(ws + 46080);                    // 32*720 ints
    u64*   sup    = (u64*)(ws + 69120);                    // 32*714*12 u64, ends @617472
    float* xsel   = ws + 617472;                           // 32*720 floats, ends @640512

    k_gather_split<<<dim3(2688),       dim3(256), 0, stream>>>(feat, A1hi, A1lo);
    k_gemm1m      <<<dim3(16, 21),     dim3(256), 0, stream>>>(A1hi, A1lo, Wconv, bconv, A2hi, A2lo);
    k_gemm2m      <<<dim3(20, 21),     dim3(256), 0, stream>>>(A2hi, A2lo, Wcls, bcls, Wreg, breg, C2);
    k_assemble    <<<dim3(MTOT),       dim3(256), 0, stream>>>(C2, AD, outP, outS, startv, endv, xsel);
    k_sort        <<<dim3(NB),         dim3(256), 0, stream>>>(outS, order);
    k_supmat      <<<dim3(12, 12, NB), dim3(256), 0, stream>>>(outP, startv, endv, xsel, order, sup);
    k_scan        <<<dim3(NB),         dim3(64),  0, stream>>>(sup, order, outK);
}

// Round 10
// 231.058 us; speedup vs baseline: 1.2010x; 1.2010x over previous
//
#include <hip/hip_runtime.h>
#include <math.h>

#define NB     32
#define FH     11
#define FW     20
#define CIN    512
#define CMID   1024
#define NANG   17
#define NPREDD 77
#define NEDGE  42
#define NPROPP 714
#define NOFF   72
#define NCLS   34
#define NREGR  1241
#define N2PAD  1280
#define MTOT   1344      // NB * NEDGE
#define NSTRIPSF 71.0f
#define PADK   40        // padded LDS row length in bf16 units (conflict-free b128)

typedef unsigned long long u64;
typedef unsigned short ushortt;
typedef short s8v __attribute__((ext_vector_type(8)));
typedef float f4v __attribute__((ext_vector_type(4)));

__device__ inline ushortt f2bf(float f) {          // RNE fp32 -> bf16
    unsigned u = __float_as_uint(f);
    u += 0x7fffu + ((u >> 16) & 1u);
    return (ushortt)(u >> 16);
}
__device__ inline float bf2f(ushortt h) {
    return __uint_as_float(((unsigned)h) << 16);
}

// ------------- gather edge pixels + split to hi/lo bf16: A1[m][c] -------------
__global__ __launch_bounds__(256) void k_gather_split(const float* __restrict__ feat,
                                                      ushortt* __restrict__ Ahi,
                                                      ushortt* __restrict__ Alo)
{
    int idx = blockIdx.x * 256 + threadIdx.x;    // exactly MTOT*CIN = 688128
    int m = idx >> 9, c = idx & 511;
    int b = m / NEDGE, e = m - b * NEDGE;
    int h, w;
    if (e < FH)          { h = e;      w = 0;      }
    else if (e < 2 * FH) { h = e - FH; w = FW - 1; }
    else                 { h = FH - 1; w = e - 2 * FH; }
    float v = feat[((size_t)(b * CIN + c) * FH + h) * FW + w];
    ushortt hi = f2bf(v);
    Ahi[idx] = hi;
    Alo[idx] = f2bf(v - bf2f(hi));
}

// ------------- GEMM1 (MFMA): [1344][1024] = A1 x Wconv^T + bconv, out hi/lo bf16 ---
__global__ __launch_bounds__(256) void k_gemm1m(const ushortt* __restrict__ Ahi,
                                                const ushortt* __restrict__ Alo,
                                                const float* __restrict__ W,
                                                const float* __restrict__ bias,
                                                ushortt* __restrict__ Chi,
                                                ushortt* __restrict__ Clo)
{
    const int K = CIN, N = CMID;
    __shared__ __align__(16) ushortt Ash[64 * PADK], Asl[64 * PADK];
    __shared__ __align__(16) ushortt Bsh[64 * PADK], Bsl[64 * PADK];
    int tid = threadIdx.x;
    int m0 = blockIdx.y * 64, n0 = blockIdx.x * 64;
    int srow = tid >> 2, sg = tid & 3;
    int lane = tid & 63, wv = tid >> 6;
    int wm = (wv & 1) * 32, wn = (wv >> 1) * 32;
    int quad = lane >> 4, l15 = lane & 15;

    f4v acc[2][2];
#pragma unroll
    for (int i = 0; i < 2; ++i)
#pragma unroll
        for (int j = 0; j < 2; ++j) acc[i][j] = (f4v){0.f, 0.f, 0.f, 0.f};

    const ushortt* Ahp = Ahi + (size_t)(m0 + srow) * K + sg * 8;
    const ushortt* Alp = Alo + (size_t)(m0 + srow) * K + sg * 8;
    const float*   Wp  = W   + (size_t)(n0 + srow) * K + sg * 8;

    for (int k0 = 0; k0 < K; k0 += 32) {
        __syncthreads();
        s8v av = *(const s8v*)(Ahp + k0);
        s8v lv = *(const s8v*)(Alp + k0);
        float4 w0 = *(const float4*)(Wp + k0);
        float4 w1 = *(const float4*)(Wp + k0 + 4);
        float wf[8] = {w0.x, w0.y, w0.z, w0.w, w1.x, w1.y, w1.z, w1.w};
        s8v wh, wl;
#pragma unroll
        for (int j = 0; j < 8; ++j) {
            ushortt h = f2bf(wf[j]);
            wh[j] = (short)h;
            wl[j] = (short)f2bf(wf[j] - bf2f(h));
        }
        *(s8v*)&Ash[srow * PADK + sg * 8] = av;
        *(s8v*)&Asl[srow * PADK + sg * 8] = lv;
        *(s8v*)&Bsh[srow * PADK + sg * 8] = wh;
        *(s8v*)&Bsl[srow * PADK + sg * 8] = wl;
        __syncthreads();
        s8v ah[2], al[2], bh[2], bl[2];
#pragma unroll
        for (int s = 0; s < 2; ++s) {
            ah[s] = *(const s8v*)&Ash[(wm + s * 16 + l15) * PADK + quad * 8];
            al[s] = *(const s8v*)&Asl[(wm + s * 16 + l15) * PADK + quad * 8];
            bh[s] = *(const s8v*)&Bsh[(wn + s * 16 + l15) * PADK + quad * 8];
            bl[s] = *(const s8v*)&Bsl[(wn + s * 16 + l15) * PADK + quad * 8];
        }
#pragma unroll
        for (int sm = 0; sm < 2; ++sm)
#pragma unroll
            for (int sn = 0; sn < 2; ++sn) {
                acc[sm][sn] = __builtin_amdgcn_mfma_f32_16x16x32_bf16(al[sm], bl[sn], acc[sm][sn], 0, 0, 0);
                acc[sm][sn] = __builtin_amdgcn_mfma_f32_16x16x32_bf16(al[sm], bh[sn], acc[sm][sn], 0, 0, 0);
                acc[sm][sn] = __builtin_amdgcn_mfma_f32_16x16x32_bf16(ah[sm], bl[sn], acc[sm][sn], 0, 0, 0);
                acc[sm][sn] = __builtin_amdgcn_mfma_f32_16x16x32_bf16(ah[sm], bh[sn], acc[sm][sn], 0, 0, 0);
            }
    }
#pragma unroll
    for (int sm = 0; sm < 2; ++sm)
#pragma unroll
        for (int sn = 0; sn < 2; ++sn)
#pragma unroll
            for (int r = 0; r < 4; ++r) {
                int m = m0 + wm + sm * 16 + quad * 4 + r;
                int n = n0 + wn + sn * 16 + l15;
                float v = acc[sm][sn][r] + bias[n];
                ushortt h = f2bf(v);
                Chi[(size_t)m * N + n] = h;
                Clo[(size_t)m * N + n] = f2bf(v - bf2f(h));
            }
}

// ------------- GEMM2 (MFMA): C2[1344][1280] = A2 x [Wcls;Wreg;0]^T + bias, fp32 out ---
__global__ __launch_bounds__(256) void k_gemm2m(const ushortt* __restrict__ Ahi,
                                                const ushortt* __restrict__ Alo,
                                                const float* __restrict__ Wcls,
                                                const float* __restrict__ bcls,
                                                const float* __restrict__ Wreg,
                                                const float* __restrict__ breg,
                                                float* __restrict__ C)
{
    const int K = CMID;
    __shared__ __align__(16) ushortt Ash[64 * PADK], Asl[64 * PADK];
    __shared__ __align__(16) ushortt Bsh[64 * PADK], Bsl[64 * PADK];
    int tid = threadIdx.x;
    int m0 = blockIdx.y * 64, n0 = blockIdx.x * 64;
    int srow = tid >> 2, sg = tid & 3;
    int lane = tid & 63, wv = tid >> 6;
    int wm = (wv & 1) * 32, wn = (wv >> 1) * 32;
    int quad = lane >> 4, l15 = lane & 15;

    f4v acc[2][2];
#pragma unroll
    for (int i = 0; i < 2; ++i)
#pragma unroll
        for (int j = 0; j < 2; ++j) acc[i][j] = (f4v){0.f, 0.f, 0.f, 0.f};

    const ushortt* Ahp = Ahi + (size_t)(m0 + srow) * K + sg * 8;
    const ushortt* Alp = Alo + (size_t)(m0 + srow) * K + sg * 8;
    int nrow = n0 + srow;
    const float* Wp = Wcls;
    bool wvalid = true;
    if (nrow < NCLS)              Wp = Wcls + (size_t)nrow * K + sg * 8;
    else if (nrow < NCLS + NREGR) Wp = Wreg + (size_t)(nrow - NCLS) * K + sg * 8;
    else                          wvalid = false;

    for (int k0 = 0; k0 < K; k0 += 32) {
        __syncthreads();
        s8v av = *(const s8v*)(Ahp + k0);
        s8v lv = *(const s8v*)(Alp + k0);
        float4 w0, w1;
        if (wvalid) {
            w0 = *(const float4*)(Wp + k0);
            w1 = *(const float4*)(Wp + k0 + 4);
        } else {
            w0 = make_float4(0.f, 0.f, 0.f, 0.f);
            w1 = w0;
        }
        float wf[8] = {w0.x, w0.y, w0.z, w0.w, w1.x, w1.y, w1.z, w1.w};
        s8v wh, wl;
#pragma unroll
        for (int j = 0; j < 8; ++j) {
            ushortt h = f2bf(wf[j]);
            wh[j] = (short)h;
            wl[j] = (short)f2bf(wf[j] - bf2f(h));
        }
        *(s8v*)&Ash[srow * PADK + sg * 8] = av;
        *(s8v*)&Asl[srow * PADK + sg * 8] = lv;
        *(s8v*)&Bsh[srow * PADK + sg * 8] = wh;
        *(s8v*)&Bsl[srow * PADK + sg * 8] = wl;
        __syncthreads();
        s8v ah[2], al[2], bh[2], bl[2];
#pragma unroll
        for (int s = 0; s < 2; ++s) {
            ah[s] = *(const s8v*)&Ash[(wm + s * 16 + l15) * PADK + quad * 8];
            al[s] = *(const s8v*)&Asl[(wm + s * 16 + l15) * PADK + quad * 8];
            bh[s] = *(const s8v*)&Bsh[(wn + s * 16 + l15) * PADK + quad * 8];
            bl[s] = *(const s8v*)&Bsl[(wn + s * 16 + l15) * PADK + quad * 8];
        }
#pragma unroll
        for (int sm = 0; sm < 2; ++sm)
#pragma unroll
            for (int sn = 0; sn < 2; ++sn) {
                acc[sm][sn] = __builtin_amdgcn_mfma_f32_16x16x32_bf16(al[sm], bl[sn], acc[sm][sn], 0, 0, 0);
                acc[sm][sn] = __builtin_amdgcn_mfma_f32_16x16x32_bf16(al[sm], bh[sn], acc[sm][sn], 0, 0, 0);
                acc[sm][sn] = __builtin_amdgcn_mfma_f32_16x16x32_bf16(ah[sm], bl[sn], acc[sm][sn], 0, 0, 0);
                acc[sm][sn] = __builtin_amdgcn_mfma_f32_16x16x32_bf16(ah[sm], bh[sn], acc[sm][sn], 0, 0, 0);
            }
    }
#pragma unroll
    for (int sm = 0; sm < 2; ++sm)
#pragma unroll
        for (int sn = 0; sn < 2; ++sn)
#pragma unroll
            for (int r = 0; r < 4; ++r) {
                int m = m0 + wm + sm * 16 + quad * 4 + r;
                int n = n0 + wn + sn * 16 + l15;
                float bb = (n < NCLS) ? bcls[n] : ((n < NCLS + NREGR) ? breg[n - NCLS] : 0.f);
                C[(size_t)m * N2PAD + n] = acc[sm][sn][r] + bb;
            }
}

// ---------------- assemble proposals + scores + start/end + xsel ----------------
__global__ __launch_bounds__(256) void k_assemble(const float* __restrict__ C2,
                                                  const float* __restrict__ AD,
                                                  float* __restrict__ outP,
                                                  float* __restrict__ outS,
                                                  float* __restrict__ startv,
                                                  float* __restrict__ endv,
                                                  float* __restrict__ xsel)
{
    int mb = blockIdx.x;                 // 0..1343
    int b = mb / NEDGE, e = mb - b * NEDGE;
    const float* c2 = C2 + (size_t)mb * N2PAD;
    int tid = threadIdx.x;
    for (int idx = tid; idx < NANG * NPREDD; idx += 256) {
        int a = idx / NPREDD, p = idx - a * NPREDD;
        int prop = e * NANG + a;
        float v;
        if (p < 2) v = c2[a * 2 + p];
        else {
            v = AD[prop * NPREDD + p];
            if (p >= 4) v += c2[NCLS + a * 73 + (p - 4)];
        }
        outP[((size_t)b * NPROPP + prop) * NPREDD + p] = v;
    }
    if (tid < NANG) {
        int a = tid, prop = e * NANG + a;
        float c0 = c2[2 * a], c1 = c2[2 * a + 1];
        float mx = fmaxf(c0, c1);
        float e0 = expf(c0 - mx), e1 = expf(c1 - mx);
        outS[b * NPROPP + prop] = e1 / (e0 + e1);
        float p2 = AD[prop * NPREDD + 2];
        float p4 = AD[prop * NPREDD + 4] + c2[NCLS + a * 73];
        float st = fminf(fmaxf(rintf(p2 * NSTRIPSF), 0.0f), NSTRIPSF);  // round half-to-even
        float en = fminf(fmaxf(st + p4 - 1.0f, 0.0f), NSTRIPSF);
        startv[b * 720 + prop] = st;
        endv[b * 720 + prop] = en;
        int ksi = (int)st;
        // bit-identical to outP[..][5+ksi]
        xsel[b * 720 + prop] = AD[prop * NPREDD + 5 + ksi] + c2[NCLS + a * 73 + ksi + 1];
    }
}

// ---------------- per-batch stable descending rank sort ----------------
__global__ __launch_bounds__(256) void k_sort(const float* __restrict__ scores,
                                              int* __restrict__ order)
{
    int b = blockIdx.x, tid = threadIdx.x;
    __shared__ float s[NPROPP];
    for (int i = tid; i < NPROPP; i += 256) s[i] = scores[b * NPROPP + i];
    __syncthreads();
    for (int i = tid; i < NPROPP; i += 256) {
        float si = s[i];
        int r = 0;
        for (int j = 0; j < NPROPP; ++j) {
            float sj = s[j];
            r += (sj > si) || (sj == si && j < i);
        }
        order[b * 720 + r] = i;
    }
}

// ---------------- suppression matrix, 64x64 tiles, xsel fast path ----------------
__global__ __launch_bounds__(256) void k_supmat(const float* __restrict__ outP,
                                                const float* __restrict__ startv,
                                                const float* __restrict__ endv,
                                                const float* __restrict__ xsel,
                                                const int* __restrict__ order,
                                                u64* __restrict__ sup)
{
    int jt = blockIdx.x, it = blockIdx.y, b = blockIdx.z;
    int i0 = it * 64, j0 = jt * 64;
    int tid = threadIdx.x;
    if (j0 + 63 < i0) {                  // strictly below diagonal: zero words
        if (tid < 64) {
            int il = i0 + tid;
            if (il < NPROPP) sup[((size_t)b * NPROPP + il) * 12 + jt] = 0ull;
        }
        return;
    }
    __shared__ float SI[64], EI[64], XI[64];
    __shared__ float SJ[64], EJ[64], XJ[64];
    __shared__ int   OI[64], OJ[64];
    if (tid < 128) {
        int side = tid >> 6, q = tid & 63;
        int pos = (side ? j0 : i0) + q;
        int o = (pos < NPROPP) ? order[b * 720 + pos] : -1;
        float st = (o >= 0) ? startv[b * 720 + o] : 0.f;
        float en = (o >= 0) ? endv[b * 720 + o] : -2.f;   // cnt<=-1 -> never suppress
        float xv = (o >= 0) ? xsel[b * 720 + o] : 0.f;
        if (!side) { SI[q] = st; EI[q] = en; XI[q] = xv; OI[q] = o; }
        else       { SJ[q] = st; EJ[q] = en; XJ[q] = xv; OJ[q] = o; }
    }
    __syncthreads();
    int lane = tid & 63, w = tid >> 6;
    int j = j0 + lane;
    float sj = SJ[lane], ej = EJ[lane], xj = XJ[lane];
    const float* basexs = outP + (size_t)b * NPROPP * NPREDD + 5;
#pragma unroll 1
    for (int rep = 0; rep < 16; ++rep) {
        int iloc = w * 16 + rep;
        int il = i0 + iloc;
        float si = SI[iloc], ei = EI[iloc];
        float s = fmaxf(si, sj), e = fminf(ei, ej);
        float cnt = e - s + 1.0f;
        bool sp = false;
        if (cnt > 0.f) {
            if (e < s) {
                sp = true;                               // empty range: dist = 0
            } else {
                int ks = (int)s, ke = (int)e;
                if (si == sj && ke == ks) {
                    sp = (fabsf(XI[iloc] - xj) / fmaxf(cnt, 1.0f)) < 15.0f;
                } else {                                  // rare general case
                    const float* xi  = basexs + (size_t)OI[iloc] * NPREDD;
                    const float* xjp = basexs + (size_t)OJ[lane] * NPREDD;
                    float sum = 0.f;
                    for (int k = ks; k <= ke; ++k)
                        sum += fabsf(xi[k] - xjp[k]);
                    sp = (sum / fmaxf(cnt, 1.0f)) < 15.0f;
                }
            }
        }
        bool valid = (il < NPROPP) && (j < NPROPP) && (j > il);
        u64 msk = __ballot(valid && sp);
        if (lane == 0 && il < NPROPP)
            sup[((size_t)b * NPROPP + il) * 12 + jt] = msk;
    }
}

// ---------------- sequential NMS scan (per batch, 1 wave) ----------------
// Fully-unrolled branchless scan. Per chunk: one 12-shuffle butterfly reduces
// the per-lane deferred accumulator P[c] into the uniform seed S0; then a
// 64x-unrolled S0-only recurrence (readlane lane indices are compile-time
// immediates; the 128 readlanes depend only on cur[0] and schedule off the
// 5-SALU/iter chain); words 1..11 are deferred per-lane: P[c+t] |= cur[t]&keep.
// No branches, no LDS atomics, no dynamic-index readlanes in the hot path.
__global__ __launch_bounds__(64) void k_scan(const u64* __restrict__ sup,
                                             const int* __restrict__ order,
                                             float* __restrict__ keep_out)
{
    int b = blockIdx.x, lane = threadIdx.x;
    __shared__ float keepv[NPROPP];
    __shared__ int ord[NPROPP];
    for (int x = lane; x < NPROPP; x += 64) { keepv[x] = 0.f; ord[x] = order[b * 720 + x]; }
    __syncthreads();
    const u64* base = sup + (size_t)b * NPROPP * 12;

    u64 P[12];
#pragma unroll
    for (int t = 0; t < 12; ++t) P[t] = 0ull;

    u64 cur[12], nxt[12];
    {   // chunk 0, shifted: cur[t] = word t of sorted row `lane`
        int r = lane;
#pragma unroll
        for (int t = 0; t < 12; ++t)
            cur[t] = (r < NPROPP) ? base[(size_t)r * 12 + t] : 0ull;
    }

#pragma unroll
    for (int c = 0; c < 12; ++c) {
        if (c < 11) {       // prefetch next chunk, shifted by (c+1)
            int r = (c + 1) * 64 + lane;
#pragma unroll
            for (int t = 0; t < 12; ++t) {
                int w = c + 1 + t;
                nxt[t] = (r < NPROPP && w < 12) ? base[(size_t)r * 12 + w] : 0ull;
            }
        }
        // reduce deferred accumulator for this chunk across lanes -> uniform S0
        unsigned plo = (unsigned)P[c], phi = (unsigned)(P[c] >> 32);
#pragma unroll
        for (int s = 1; s < 64; s <<= 1) {
            plo |= __shfl_xor(plo, s, 64);
            phi |= __shfl_xor(phi, s, 64);
        }
        u64 S0 = ((u64)phi << 32) | (u64)plo;
        u64 c0 = cur[0];
        u64 keepbits = 0ull;
#pragma unroll
        for (int ib = 0; ib < 64; ++ib) {   // static ib -> immediate-lane readlane
            u64 row = ((u64)(unsigned)__builtin_amdgcn_readlane((int)(c0 >> 32), ib) << 32)
                    |  (u64)(unsigned)__builtin_amdgcn_readlane((int)(unsigned)c0, ib);
            u64 m = ((S0 >> ib) & 1ull) - 1ull;   // ~0 if keep, 0 if suppressed
            S0 |= row & m;                        // row has only bits > ib
            keepbits |= m & (1ull << ib);
        }
        int imax = NPROPP - c * 64; if (imax > 64) imax = 64;
        if (lane < imax)
            keepv[ord[c * 64 + lane]] = ((keepbits >> lane) & 1ull) ? 1.f : 0.f;
        // defer this chunk's kept-row contributions to future chunks (per-lane)
        u64 lm = 0ull - ((keepbits >> lane) & 1ull);
#pragma unroll
        for (int t = 1; t < 12; ++t)
            if (c + t < 12) P[c + t] |= cur[t] & lm;   // OOB rows have cur==0
#pragma unroll
        for (int t = 0; t < 12; ++t) cur[t] = nxt[t];
    }
    __syncthreads();
    for (int x = lane; x < NPROPP; x += 64) keep_out[b * NPROPP + x] = keepv[x];
}

extern "C" void kernel_launch(void* const* d_in, const int* in_sizes, int n_in,
                              void* d_out, int out_size, void* d_ws, size_t ws_size,
                              hipStream_t stream)
{
    const float* feat  = (const float*)d_in[0];
    const float* Wconv = (const float*)d_in[1];
    const float* bconv = (const float*)d_in[2];
    const float* Wcls  = (const float*)d_in[3];
    const float* bcls  = (const float*)d_in[4];
    const float* Wreg  = (const float*)d_in[5];
    const float* breg  = (const float*)d_in[6];
    const float* AD    = (const float*)d_in[8];   // anchors_anchor_dim (714,77)

    float* out  = (float*)d_out;
    float* outP = out;                                     // proposals 32*714*77
    float* outK = out + (size_t)NB * NPROPP * NPREDD;      // keep mask  32*714
    float* outS = outK + (size_t)NB * NPROPP;              // scores     32*714

    float* ws = (float*)d_ws;
    // [0, 688128) floats: A1hi/A1lo bf16 (dead after gemm1) -> NMS scratch later
    ushortt* A1hi = (ushortt*)ws;                          // 688128 bf16
    ushortt* A1lo = (ushortt*)(ws + 344064);               // 688128 bf16
    ushortt* A2hi = (ushortt*)(ws + 688128);               // 1344*1024 bf16
    ushortt* A2lo = (ushortt*)(ws + 1376256);              // 1344*1024 bf16
    float*   C2   = ws + 2064384;                          // 1344*1280 fp32, ends 3784704
    // NMS scratch overlays dead A1 region:
    float* startv = ws;                                    // 32*720 floats
    float* endv   = ws + 23040;                            // 32*720 floats
    int*   order  = (int*)(ws + 46080);                    // 32*720 ints
    u64*   sup    = (u64*)(ws + 69120);                    // 32*714*12 u64, ends @617472
    float* xsel   = ws + 617472;                           // 32*720 floats, ends @640512

    k_gather_split<<<dim3(2688),       dim3(256), 0, stream>>>(feat, A1hi, A1lo);
    k_gemm1m      <<<dim3(16, 21),     dim3(256), 0, stream>>>(A1hi, A1lo, Wconv, bconv, A2hi, A2lo);
    k_gemm2m      <<<dim3(20, 21),     dim3(256), 0, stream>>>(A2hi, A2lo, Wcls, bcls, Wreg, breg, C2);
    k_assemble    <<<dim3(MTOT),       dim3(256), 0, stream>>>(C2, AD, outP, outS, startv, endv, xsel);
    k_sort        <<<dim3(NB),         dim3(256), 0, stream>>>(outS, order);
    k_supmat      <<<dim3(12, 12, NB), dim3(256), 0, stream>>>(outP, startv, endv, xsel, order, sup);
    k_scan        <<<dim3(NB),         dim3(64),  0, stream>>>(sup, order, outK);
}

// Round 11
// 208.617 us; speedup vs baseline: 1.3301x; 1.1076x over previous
//
#include <hip/hip_runtime.h>
#include <math.h>

#define NB     32
#define FH     11
#define FW     20
#define CIN    512
#define CMID   1024
#define NANG   17
#define NPREDD 77
#define NEDGE  42
#define NPROPP 714
#define NOFF   72
#define NCLS   34
#define NREGR  1241
#define N2PAD  1280
#define MTOT   1344      // NB * NEDGE
#define NSTRIPSF 71.0f
#define PADK   40        // padded LDS row length in bf16 units (conflict-free b128)

typedef unsigned long long u64;
typedef unsigned short ushortt;
typedef short s8v __attribute__((ext_vector_type(8)));
typedef float f4v __attribute__((ext_vector_type(4)));

__device__ inline ushortt f2bf(float f) {          // RNE fp32 -> bf16
    unsigned u = __float_as_uint(f);
    u += 0x7fffu + ((u >> 16) & 1u);
    return (ushortt)(u >> 16);
}
__device__ inline float bf2f(ushortt h) {
    return __uint_as_float(((unsigned)h) << 16);
}

// ------------- gather edge pixels + split to hi/lo bf16: A1[m][c] -------------
__global__ __launch_bounds__(256) void k_gather_split(const float* __restrict__ feat,
                                                      ushortt* __restrict__ Ahi,
                                                      ushortt* __restrict__ Alo)
{
    int idx = blockIdx.x * 256 + threadIdx.x;    // exactly MTOT*CIN = 688128
    int m = idx >> 9, c = idx & 511;
    int b = m / NEDGE, e = m - b * NEDGE;
    int h, w;
    if (e < FH)          { h = e;      w = 0;      }
    else if (e < 2 * FH) { h = e - FH; w = FW - 1; }
    else                 { h = FH - 1; w = e - 2 * FH; }
    float v = feat[((size_t)(b * CIN + c) * FH + h) * FW + w];
    ushortt hi = f2bf(v);
    Ahi[idx] = hi;
    Alo[idx] = f2bf(v - bf2f(hi));
}

// ------------- GEMM1 (MFMA): [1344][1024] = A1 x Wconv^T + bconv, out hi/lo bf16 ---
__global__ __launch_bounds__(256) void k_gemm1m(const ushortt* __restrict__ Ahi,
                                                const ushortt* __restrict__ Alo,
                                                const float* __restrict__ W,
                                                const float* __restrict__ bias,
                                                ushortt* __restrict__ Chi,
                                                ushortt* __restrict__ Clo)
{
    const int K = CIN, N = CMID;
    __shared__ __align__(16) ushortt Ash[64 * PADK], Asl[64 * PADK];
    __shared__ __align__(16) ushortt Bsh[64 * PADK], Bsl[64 * PADK];
    int tid = threadIdx.x;
    int m0 = blockIdx.y * 64, n0 = blockIdx.x * 64;
    int srow = tid >> 2, sg = tid & 3;
    int lane = tid & 63, wv = tid >> 6;
    int wm = (wv & 1) * 32, wn = (wv >> 1) * 32;
    int quad = lane >> 4, l15 = lane & 15;

    f4v acc[2][2];
#pragma unroll
    for (int i = 0; i < 2; ++i)
#pragma unroll
        for (int j = 0; j < 2; ++j) acc[i][j] = (f4v){0.f, 0.f, 0.f, 0.f};

    const ushortt* Ahp = Ahi + (size_t)(m0 + srow) * K + sg * 8;
    const ushortt* Alp = Alo + (size_t)(m0 + srow) * K + sg * 8;
    const float*   Wp  = W   + (size_t)(n0 + srow) * K + sg * 8;

    for (int k0 = 0; k0 < K; k0 += 32) {
        __syncthreads();
        s8v av = *(const s8v*)(Ahp + k0);
        s8v lv = *(const s8v*)(Alp + k0);
        float4 w0 = *(const float4*)(Wp + k0);
        float4 w1 = *(const float4*)(Wp + k0 + 4);
        float wf[8] = {w0.x, w0.y, w0.z, w0.w, w1.x, w1.y, w1.z, w1.w};
        s8v wh, wl;
#pragma unroll
        for (int j = 0; j < 8; ++j) {
            ushortt h = f2bf(wf[j]);
            wh[j] = (short)h;
            wl[j] = (short)f2bf(wf[j] - bf2f(h));
        }
        *(s8v*)&Ash[srow * PADK + sg * 8] = av;
        *(s8v*)&Asl[srow * PADK + sg * 8] = lv;
        *(s8v*)&Bsh[srow * PADK + sg * 8] = wh;
        *(s8v*)&Bsl[srow * PADK + sg * 8] = wl;
        __syncthreads();
        s8v ah[2], al[2], bh[2], bl[2];
#pragma unroll
        for (int s = 0; s < 2; ++s) {
            ah[s] = *(const s8v*)&Ash[(wm + s * 16 + l15) * PADK + quad * 8];
            al[s] = *(const s8v*)&Asl[(wm + s * 16 + l15) * PADK + quad * 8];
            bh[s] = *(const s8v*)&Bsh[(wn + s * 16 + l15) * PADK + quad * 8];
            bl[s] = *(const s8v*)&Bsl[(wn + s * 16 + l15) * PADK + quad * 8];
        }
#pragma unroll
        for (int sm = 0; sm < 2; ++sm)
#pragma unroll
            for (int sn = 0; sn < 2; ++sn) {
                acc[sm][sn] = __builtin_amdgcn_mfma_f32_16x16x32_bf16(al[sm], bl[sn], acc[sm][sn], 0, 0, 0);
                acc[sm][sn] = __builtin_amdgcn_mfma_f32_16x16x32_bf16(al[sm], bh[sn], acc[sm][sn], 0, 0, 0);
                acc[sm][sn] = __builtin_amdgcn_mfma_f32_16x16x32_bf16(ah[sm], bl[sn], acc[sm][sn], 0, 0, 0);
                acc[sm][sn] = __builtin_amdgcn_mfma_f32_16x16x32_bf16(ah[sm], bh[sn], acc[sm][sn], 0, 0, 0);
            }
    }
#pragma unroll
    for (int sm = 0; sm < 2; ++sm)
#pragma unroll
        for (int sn = 0; sn < 2; ++sn)
#pragma unroll
            for (int r = 0; r < 4; ++r) {
                int m = m0 + wm + sm * 16 + quad * 4 + r;
                int n = n0 + wn + sn * 16 + l15;
                float v = acc[sm][sn][r] + bias[n];
                ushortt h = f2bf(v);
                Chi[(size_t)m * N + n] = h;
                Clo[(size_t)m * N + n] = f2bf(v - bf2f(h));
            }
}

// ------------- GEMM2 (MFMA): C2[1344][1280] = A2 x [Wcls;Wreg;0]^T + bias, fp32 out ---
__global__ __launch_bounds__(256) void k_gemm2m(const ushortt* __restrict__ Ahi,
                                                const ushortt* __restrict__ Alo,
                                                const float* __restrict__ Wcls,
                                                const float* __restrict__ bcls,
                                                const float* __restrict__ Wreg,
                                                const float* __restrict__ breg,
                                                float* __restrict__ C)
{
    const int K = CMID;
    __shared__ __align__(16) ushortt Ash[64 * PADK], Asl[64 * PADK];
    __shared__ __align__(16) ushortt Bsh[64 * PADK], Bsl[64 * PADK];
    int tid = threadIdx.x;
    int m0 = blockIdx.y * 64, n0 = blockIdx.x * 64;
    int srow = tid >> 2, sg = tid & 3;
    int lane = tid & 63, wv = tid >> 6;
    int wm = (wv & 1) * 32, wn = (wv >> 1) * 32;
    int quad = lane >> 4, l15 = lane & 15;

    f4v acc[2][2];
#pragma unroll
    for (int i = 0; i < 2; ++i)
#pragma unroll
        for (int j = 0; j < 2; ++j) acc[i][j] = (f4v){0.f, 0.f, 0.f, 0.f};

    const ushortt* Ahp = Ahi + (size_t)(m0 + srow) * K + sg * 8;
    const ushortt* Alp = Alo + (size_t)(m0 + srow) * K + sg * 8;
    int nrow = n0 + srow;
    const float* Wp = Wcls;
    bool wvalid = true;
    if (nrow < NCLS)              Wp = Wcls + (size_t)nrow * K + sg * 8;
    else if (nrow < NCLS + NREGR) Wp = Wreg + (size_t)(nrow - NCLS) * K + sg * 8;
    else                          wvalid = false;

    for (int k0 = 0; k0 < K; k0 += 32) {
        __syncthreads();
        s8v av = *(const s8v*)(Ahp + k0);
        s8v lv = *(const s8v*)(Alp + k0);
        float4 w0, w1;
        if (wvalid) {
            w0 = *(const float4*)(Wp + k0);
            w1 = *(const float4*)(Wp + k0 + 4);
        } else {
            w0 = make_float4(0.f, 0.f, 0.f, 0.f);
            w1 = w0;
        }
        float wf[8] = {w0.x, w0.y, w0.z, w0.w, w1.x, w1.y, w1.z, w1.w};
        s8v wh, wl;
#pragma unroll
        for (int j = 0; j < 8; ++j) {
            ushortt h = f2bf(wf[j]);
            wh[j] = (short)h;
            wl[j] = (short)f2bf(wf[j] - bf2f(h));
        }
        *(s8v*)&Ash[srow * PADK + sg * 8] = av;
        *(s8v*)&Asl[srow * PADK + sg * 8] = lv;
        *(s8v*)&Bsh[srow * PADK + sg * 8] = wh;
        *(s8v*)&Bsl[srow * PADK + sg * 8] = wl;
        __syncthreads();
        s8v ah[2], al[2], bh[2], bl[2];
#pragma unroll
        for (int s = 0; s < 2; ++s) {
            ah[s] = *(const s8v*)&Ash[(wm + s * 16 + l15) * PADK + quad * 8];
            al[s] = *(const s8v*)&Asl[(wm + s * 16 + l15) * PADK + quad * 8];
            bh[s] = *(const s8v*)&Bsh[(wn + s * 16 + l15) * PADK + quad * 8];
            bl[s] = *(const s8v*)&Bsl[(wn + s * 16 + l15) * PADK + quad * 8];
        }
#pragma unroll
        for (int sm = 0; sm < 2; ++sm)
#pragma unroll
            for (int sn = 0; sn < 2; ++sn) {
                acc[sm][sn] = __builtin_amdgcn_mfma_f32_16x16x32_bf16(al[sm], bl[sn], acc[sm][sn], 0, 0, 0);
                acc[sm][sn] = __builtin_amdgcn_mfma_f32_16x16x32_bf16(al[sm], bh[sn], acc[sm][sn], 0, 0, 0);
                acc[sm][sn] = __builtin_amdgcn_mfma_f32_16x16x32_bf16(ah[sm], bl[sn], acc[sm][sn], 0, 0, 0);
                acc[sm][sn] = __builtin_amdgcn_mfma_f32_16x16x32_bf16(ah[sm], bh[sn], acc[sm][sn], 0, 0, 0);
            }
    }
#pragma unroll
    for (int sm = 0; sm < 2; ++sm)
#pragma unroll
        for (int sn = 0; sn < 2; ++sn)
#pragma unroll
            for (int r = 0; r < 4; ++r) {
                int m = m0 + wm + sm * 16 + quad * 4 + r;
                int n = n0 + wn + sn * 16 + l15;
                float bb = (n < NCLS) ? bcls[n] : ((n < NCLS + NREGR) ? breg[n - NCLS] : 0.f);
                C[(size_t)m * N2PAD + n] = acc[sm][sn][r] + bb;
            }
}

// ---------------- assemble proposals + scores + start/end + xsel ----------------
__global__ __launch_bounds__(256) void k_assemble(const float* __restrict__ C2,
                                                  const float* __restrict__ AD,
                                                  float* __restrict__ outP,
                                                  float* __restrict__ outS,
                                                  float* __restrict__ startv,
                                                  float* __restrict__ endv,
                                                  float* __restrict__ xsel)
{
    int mb = blockIdx.x;                 // 0..1343
    int b = mb / NEDGE, e = mb - b * NEDGE;
    const float* c2 = C2 + (size_t)mb * N2PAD;
    int tid = threadIdx.x;
    for (int idx = tid; idx < NANG * NPREDD; idx += 256) {
        int a = idx / NPREDD, p = idx - a * NPREDD;
        int prop = e * NANG + a;
        float v;
        if (p < 2) v = c2[a * 2 + p];
        else {
            v = AD[prop * NPREDD + p];
            if (p >= 4) v += c2[NCLS + a * 73 + (p - 4)];
        }
        outP[((size_t)b * NPROPP + prop) * NPREDD + p] = v;
    }
    if (tid < NANG) {
        int a = tid, prop = e * NANG + a;
        float c0 = c2[2 * a], c1 = c2[2 * a + 1];
        float mx = fmaxf(c0, c1);
        float e0 = expf(c0 - mx), e1 = expf(c1 - mx);
        outS[b * NPROPP + prop] = e1 / (e0 + e1);
        float p2 = AD[prop * NPREDD + 2];
        float p4 = AD[prop * NPREDD + 4] + c2[NCLS + a * 73];
        float st = fminf(fmaxf(rintf(p2 * NSTRIPSF), 0.0f), NSTRIPSF);  // round half-to-even
        float en = fminf(fmaxf(st + p4 - 1.0f, 0.0f), NSTRIPSF);
        startv[b * 720 + prop] = st;
        endv[b * 720 + prop] = en;
        int ksi = (int)st;
        // bit-identical to outP[..][5+ksi]
        xsel[b * 720 + prop] = AD[prop * NPREDD + 5 + ksi] + c2[NCLS + a * 73 + ksi + 1];
    }
}

// ---------------- per-batch stable descending rank sort (parallel tiles) -------
// Grid (NB, 6): block (b, tile) ranks i in [tile*128, tile*128+128). The j-loop
// reads the LDS score array as float4 (180 vector reads vs 714 scalar). Padded
// entries are -1e30: softmax scores are >0, so they never win or tie.
__global__ __launch_bounds__(128) void k_sort(const float* __restrict__ scores,
                                              int* __restrict__ order)
{
    int b = blockIdx.x, tile = blockIdx.y, tid = threadIdx.x;
    __shared__ __align__(16) float s[720];
    for (int x = tid; x < 720; x += 128)
        s[x] = (x < NPROPP) ? scores[b * NPROPP + x] : -1e30f;
    __syncthreads();
    int i = tile * 128 + tid;
    if (i >= NPROPP) return;
    float si = s[i];
    int r = 0;
#pragma unroll 4
    for (int j4 = 0; j4 < 720; j4 += 4) {
        float4 v = *(const float4*)&s[j4];
        r += (v.x > si) || (v.x == si && (j4 + 0) < i);
        r += (v.y > si) || (v.y == si && (j4 + 1) < i);
        r += (v.z > si) || (v.z == si && (j4 + 2) < i);
        r += (v.w > si) || (v.w == si && (j4 + 3) < i);
    }
    order[b * 720 + r] = i;
}

// ---------------- suppression matrix, 64x64 tiles, xsel fast path ----------------
__global__ __launch_bounds__(256) void k_supmat(const float* __restrict__ outP,
                                                const float* __restrict__ startv,
                                                const float* __restrict__ endv,
                                                const float* __restrict__ xsel,
                                                const int* __restrict__ order,
                                                u64* __restrict__ sup)
{
    int jt = blockIdx.x, it = blockIdx.y, b = blockIdx.z;
    int i0 = it * 64, j0 = jt * 64;
    int tid = threadIdx.x;
    if (j0 + 63 < i0) {                  // strictly below diagonal: zero words
        if (tid < 64) {
            int il = i0 + tid;
            if (il < NPROPP) sup[((size_t)b * NPROPP + il) * 12 + jt] = 0ull;
        }
        return;
    }
    __shared__ float SI[64], EI[64], XI[64];
    __shared__ float SJ[64], EJ[64], XJ[64];
    __shared__ int   OI[64], OJ[64];
    if (tid < 128) {
        int side = tid >> 6, q = tid & 63;
        int pos = (side ? j0 : i0) + q;
        int o = (pos < NPROPP) ? order[b * 720 + pos] : -1;
        float st = (o >= 0) ? startv[b * 720 + o] : 0.f;
        float en = (o >= 0) ? endv[b * 720 + o] : -2.f;   // cnt<=-1 -> never suppress
        float xv = (o >= 0) ? xsel[b * 720 + o] : 0.f;
        if (!side) { SI[q] = st; EI[q] = en; XI[q] = xv; OI[q] = o; }
        else       { SJ[q] = st; EJ[q] = en; XJ[q] = xv; OJ[q] = o; }
    }
    __syncthreads();
    int lane = tid & 63, w = tid >> 6;
    int j = j0 + lane;
    float sj = SJ[lane], ej = EJ[lane], xj = XJ[lane];
    const float* basexs = outP + (size_t)b * NPROPP * NPREDD + 5;
#pragma unroll 1
    for (int rep = 0; rep < 16; ++rep) {
        int iloc = w * 16 + rep;
        int il = i0 + iloc;
        float si = SI[iloc], ei = EI[iloc];
        float s = fmaxf(si, sj), e = fminf(ei, ej);
        float cnt = e - s + 1.0f;
        bool sp = false;
        if (cnt > 0.f) {
            if (e < s) {
                sp = true;                               // empty range: dist = 0
            } else {
                int ks = (int)s, ke = (int)e;
                if (si == sj && ke == ks) {
                    sp = (fabsf(XI[iloc] - xj) / fmaxf(cnt, 1.0f)) < 15.0f;
                } else {                                  // rare general case
                    const float* xi  = basexs + (size_t)OI[iloc] * NPREDD;
                    const float* xjp = basexs + (size_t)OJ[lane] * NPREDD;
                    float sum = 0.f;
                    for (int k = ks; k <= ke; ++k)
                        sum += fabsf(xi[k] - xjp[k]);
                    sp = (sum / fmaxf(cnt, 1.0f)) < 15.0f;
                }
            }
        }
        bool valid = (il < NPROPP) && (j < NPROPP) && (j > il);
        u64 msk = __ballot(valid && sp);
        if (lane == 0 && il < NPROPP)
            sup[((size_t)b * NPROPP + il) * 12 + jt] = msk;
    }
}

// ---------------- sequential NMS scan (per batch, 1 wave) ----------------
// Fully-unrolled branchless scan (R10 winner): per chunk one 12-shuffle
// butterfly seeds S0; 64x-unrolled S0-only recurrence with immediate-lane
// readlanes; words 1..11 deferred per-lane into P[].
__global__ __launch_bounds__(64) void k_scan(const u64* __restrict__ sup,
                                             const int* __restrict__ order,
                                             float* __restrict__ keep_out)
{
    int b = blockIdx.x, lane = threadIdx.x;
    __shared__ float keepv[NPROPP];
    __shared__ int ord[NPROPP];
    for (int x = lane; x < NPROPP; x += 64) { keepv[x] = 0.f; ord[x] = order[b * 720 + x]; }
    __syncthreads();
    const u64* base = sup + (size_t)b * NPROPP * 12;

    u64 P[12];
#pragma unroll
    for (int t = 0; t < 12; ++t) P[t] = 0ull;

    u64 cur[12], nxt[12];
    {   // chunk 0, shifted: cur[t] = word t of sorted row `lane`
        int r = lane;
#pragma unroll
        for (int t = 0; t < 12; ++t)
            cur[t] = (r < NPROPP) ? base[(size_t)r * 12 + t] : 0ull;
    }

#pragma unroll
    for (int c = 0; c < 12; ++c) {
        if (c < 11) {       // prefetch next chunk, shifted by (c+1)
            int r = (c + 1) * 64 + lane;
#pragma unroll
            for (int t = 0; t < 12; ++t) {
                int w = c + 1 + t;
                nxt[t] = (r < NPROPP && w < 12) ? base[(size_t)r * 12 + w] : 0ull;
            }
        }
        // reduce deferred accumulator for this chunk across lanes -> uniform S0
        unsigned plo = (unsigned)P[c], phi = (unsigned)(P[c] >> 32);
#pragma unroll
        for (int s = 1; s < 64; s <<= 1) {
            plo |= __shfl_xor(plo, s, 64);
            phi |= __shfl_xor(phi, s, 64);
        }
        u64 S0 = ((u64)phi << 32) | (u64)plo;
        u64 c0 = cur[0];
        u64 keepbits = 0ull;
#pragma unroll
        for (int ib = 0; ib < 64; ++ib) {   // static ib -> immediate-lane readlane
            u64 row = ((u64)(unsigned)__builtin_amdgcn_readlane((int)(c0 >> 32), ib) << 32)
                    |  (u64)(unsigned)__builtin_amdgcn_readlane((int)(unsigned)c0, ib);
            u64 m = ((S0 >> ib) & 1ull) - 1ull;   // ~0 if keep, 0 if suppressed
            S0 |= row & m;                        // row has only bits > ib
            keepbits |= m & (1ull << ib);
        }
        int imax = NPROPP - c * 64; if (imax > 64) imax = 64;
        if (lane < imax)
            keepv[ord[c * 64 + lane]] = ((keepbits >> lane) & 1ull) ? 1.f : 0.f;
        // defer this chunk's kept-row contributions to future chunks (per-lane)
        u64 lm = 0ull - ((keepbits >> lane) & 1ull);
#pragma unroll
        for (int t = 1; t < 12; ++t)
            if (c + t < 12) P[c + t] |= cur[t] & lm;   // OOB rows have cur==0
#pragma unroll
        for (int t = 0; t < 12; ++t) cur[t] = nxt[t];
    }
    __syncthreads();
    for (int x = lane; x < NPROPP; x += 64) keep_out[b * NPROPP + x] = keepv[x];
}

extern "C" void kernel_launch(void* const* d_in, const int* in_sizes, int n_in,
                              void* d_out, int out_size, void* d_ws, size_t ws_size,
                              hipStream_t stream)
{
    const float* feat  = (const float*)d_in[0];
    const float* Wconv = (const float*)d_in[1];
    const float* bconv = (const float*)d_in[2];
    const float* Wcls  = (const float*)d_in[3];
    const float* bcls  = (const float*)d_in[4];
    const float* Wreg  = (const float*)d_in[5];
    const float* breg  = (const float*)d_in[6];
    const float* AD    = (const float*)d_in[8];   // anchors_anchor_dim (714,77)

    float* out  = (float*)d_out;
    float* outP = out;                                     // proposals 32*714*77
    float* outK = out + (size_t)NB * NPROPP * NPREDD;      // keep mask  32*714
    float* outS = outK + (size_t)NB * NPROPP;              // scores     32*714

    float* ws = (float*)d_ws;
    // [0, 688128) floats: A1hi/A1lo bf16 (dead after gemm1) -> NMS scratch later
    ushortt* A1hi = (ushortt*)ws;                          // 688128 bf16
    ushortt* A1lo = (ushortt*)(ws + 344064);               // 688128 bf16
    ushortt* A2hi = (ushortt*)(ws + 688128);               // 1344*1024 bf16
    ushortt* A2lo = (ushortt*)(ws + 1376256);              // 1344*1024 bf16
    float*   C2   = ws + 2064384;                          // 1344*1280 fp32, ends 3784704
    // NMS scratch overlays dead A1 region:
    float* startv = ws;                                    // 32*720 floats
    float* endv   = ws + 23040;                            // 32*720 floats
    int*   order  = (int*)(ws + 46080);                    // 32*720 ints
    u64*   sup    = (u64*)(ws + 69120);                    // 32*714*12 u64, ends @617472
    float* xsel   = ws + 617472;                           // 32*720 floats, ends @640512

    k_gather_split<<<dim3(2688),       dim3(256), 0, stream>>>(feat, A1hi, A1lo);
    k_gemm1m      <<<dim3(16, 21),     dim3(256), 0, stream>>>(A1hi, A1lo, Wconv, bconv, A2hi, A2lo);
    k_gemm2m      <<<dim3(20, 21),     dim3(256), 0, stream>>>(A2hi, A2lo, Wcls, bcls, Wreg, breg, C2);
    k_assemble    <<<dim3(MTOT),       dim3(256), 0, stream>>>(C2, AD, outP, outS, startv, endv, xsel);
    k_sort        <<<dim3(NB, 6),      dim3(128), 0, stream>>>(outS, order);
    k_supmat      <<<dim3(12, 12, NB), dim3(256), 0, stream>>>(outP, startv, endv, xsel, order, sup);
    k_scan        <<<dim3(NB),         dim3(64),  0, stream>>>(sup, order, outK);
}

// Round 12
// 192.076 us; speedup vs baseline: 1.4447x; 1.0861x over previous
//
#include <hip/hip_runtime.h>
#include <math.h>

#define NB     32
#define FH     11
#define FW     20
#define CIN    512
#define CMID   1024
#define NANG   17
#define NPREDD 77
#define NEDGE  42
#define NPROPP 714
#define NOFF   72
#define NCLS   34
#define NREGR  1241
#define N2PAD  1280
#define MTOT   1344      // NB * NEDGE
#define NSTRIPSF 71.0f
#define PADK   40        // padded LDS row length in bf16 units (conflict-free b128)

typedef unsigned long long u64;
typedef unsigned short ushortt;
typedef short s8v __attribute__((ext_vector_type(8)));
typedef float f4v __attribute__((ext_vector_type(4)));

__device__ inline ushortt f2bf(float f) {          // RNE fp32 -> bf16
    unsigned u = __float_as_uint(f);
    u += 0x7fffu + ((u >> 16) & 1u);
    return (ushortt)(u >> 16);
}
__device__ inline float bf2f(ushortt h) {
    return __uint_as_float(((unsigned)h) << 16);
}

// ------------- gather edge pixels + split to hi/lo bf16: A1[m][c] -------------
__global__ __launch_bounds__(256) void k_gather_split(const float* __restrict__ feat,
                                                      ushortt* __restrict__ Ahi,
                                                      ushortt* __restrict__ Alo)
{
    int idx = blockIdx.x * 256 + threadIdx.x;    // exactly MTOT*CIN = 688128
    int m = idx >> 9, c = idx & 511;
    int b = m / NEDGE, e = m - b * NEDGE;
    int h, w;
    if (e < FH)          { h = e;      w = 0;      }
    else if (e < 2 * FH) { h = e - FH; w = FW - 1; }
    else                 { h = FH - 1; w = e - 2 * FH; }
    float v = feat[((size_t)(b * CIN + c) * FH + h) * FW + w];
    ushortt hi = f2bf(v);
    Ahi[idx] = hi;
    Alo[idx] = f2bf(v - bf2f(hi));
}

// ------------- GEMM1 (MFMA): [1344][1024] = A1 x Wconv^T + bconv, out hi/lo bf16 ---
__global__ __launch_bounds__(256) void k_gemm1m(const ushortt* __restrict__ Ahi,
                                                const ushortt* __restrict__ Alo,
                                                const float* __restrict__ W,
                                                const float* __restrict__ bias,
                                                ushortt* __restrict__ Chi,
                                                ushortt* __restrict__ Clo)
{
    const int K = CIN, N = CMID;
    __shared__ __align__(16) ushortt Ash[64 * PADK], Asl[64 * PADK];
    __shared__ __align__(16) ushortt Bsh[64 * PADK], Bsl[64 * PADK];
    int tid = threadIdx.x;
    int m0 = blockIdx.y * 64, n0 = blockIdx.x * 64;
    int srow = tid >> 2, sg = tid & 3;
    int lane = tid & 63, wv = tid >> 6;
    int wm = (wv & 1) * 32, wn = (wv >> 1) * 32;
    int quad = lane >> 4, l15 = lane & 15;

    f4v acc[2][2];
#pragma unroll
    for (int i = 0; i < 2; ++i)
#pragma unroll
        for (int j = 0; j < 2; ++j) acc[i][j] = (f4v){0.f, 0.f, 0.f, 0.f};

    const ushortt* Ahp = Ahi + (size_t)(m0 + srow) * K + sg * 8;
    const ushortt* Alp = Alo + (size_t)(m0 + srow) * K + sg * 8;
    const float*   Wp  = W   + (size_t)(n0 + srow) * K + sg * 8;

    for (int k0 = 0; k0 < K; k0 += 32) {
        __syncthreads();
        s8v av = *(const s8v*)(Ahp + k0);
        s8v lv = *(const s8v*)(Alp + k0);
        float4 w0 = *(const float4*)(Wp + k0);
        float4 w1 = *(const float4*)(Wp + k0 + 4);
        float wf[8] = {w0.x, w0.y, w0.z, w0.w, w1.x, w1.y, w1.z, w1.w};
        s8v wh, wl;
#pragma unroll
        for (int j = 0; j < 8; ++j) {
            ushortt h = f2bf(wf[j]);
            wh[j] = (short)h;
            wl[j] = (short)f2bf(wf[j] - bf2f(h));
        }
        *(s8v*)&Ash[srow * PADK + sg * 8] = av;
        *(s8v*)&Asl[srow * PADK + sg * 8] = lv;
        *(s8v*)&Bsh[srow * PADK + sg * 8] = wh;
        *(s8v*)&Bsl[srow * PADK + sg * 8] = wl;
        __syncthreads();
        s8v ah[2], al[2], bh[2], bl[2];
#pragma unroll
        for (int s = 0; s < 2; ++s) {
            ah[s] = *(const s8v*)&Ash[(wm + s * 16 + l15) * PADK + quad * 8];
            al[s] = *(const s8v*)&Asl[(wm + s * 16 + l15) * PADK + quad * 8];
            bh[s] = *(const s8v*)&Bsh[(wn + s * 16 + l15) * PADK + quad * 8];
            bl[s] = *(const s8v*)&Bsl[(wn + s * 16 + l15) * PADK + quad * 8];
        }
#pragma unroll
        for (int sm = 0; sm < 2; ++sm)
#pragma unroll
            for (int sn = 0; sn < 2; ++sn) {
                acc[sm][sn] = __builtin_amdgcn_mfma_f32_16x16x32_bf16(al[sm], bl[sn], acc[sm][sn], 0, 0, 0);
                acc[sm][sn] = __builtin_amdgcn_mfma_f32_16x16x32_bf16(al[sm], bh[sn], acc[sm][sn], 0, 0, 0);
                acc[sm][sn] = __builtin_amdgcn_mfma_f32_16x16x32_bf16(ah[sm], bl[sn], acc[sm][sn], 0, 0, 0);
                acc[sm][sn] = __builtin_amdgcn_mfma_f32_16x16x32_bf16(ah[sm], bh[sn], acc[sm][sn], 0, 0, 0);
            }
    }
#pragma unroll
    for (int sm = 0; sm < 2; ++sm)
#pragma unroll
        for (int sn = 0; sn < 2; ++sn)
#pragma unroll
            for (int r = 0; r < 4; ++r) {
                int m = m0 + wm + sm * 16 + quad * 4 + r;
                int n = n0 + wn + sn * 16 + l15;
                float v = acc[sm][sn][r] + bias[n];
                ushortt h = f2bf(v);
                Chi[(size_t)m * N + n] = h;
                Clo[(size_t)m * N + n] = f2bf(v - bf2f(h));
            }
}

// ------------- GEMM2 (MFMA): C2[1344][1280] = A2 x [Wcls;Wreg;0]^T + bias, fp32 out ---
__global__ __launch_bounds__(256) void k_gemm2m(const ushortt* __restrict__ Ahi,
                                                const ushortt* __restrict__ Alo,
                                                const float* __restrict__ Wcls,
                                                const float* __restrict__ bcls,
                                                const float* __restrict__ Wreg,
                                                const float* __restrict__ breg,
                                                float* __restrict__ C)
{
    const int K = CMID;
    __shared__ __align__(16) ushortt Ash[64 * PADK], Asl[64 * PADK];
    __shared__ __align__(16) ushortt Bsh[64 * PADK], Bsl[64 * PADK];
    int tid = threadIdx.x;
    int m0 = blockIdx.y * 64, n0 = blockIdx.x * 64;
    int srow = tid >> 2, sg = tid & 3;
    int lane = tid & 63, wv = tid >> 6;
    int wm = (wv & 1) * 32, wn = (wv >> 1) * 32;
    int quad = lane >> 4, l15 = lane & 15;

    f4v acc[2][2];
#pragma unroll
    for (int i = 0; i < 2; ++i)
#pragma unroll
        for (int j = 0; j < 2; ++j) acc[i][j] = (f4v){0.f, 0.f, 0.f, 0.f};

    const ushortt* Ahp = Ahi + (size_t)(m0 + srow) * K + sg * 8;
    const ushortt* Alp = Alo + (size_t)(m0 + srow) * K + sg * 8;
    int nrow = n0 + srow;
    const float* Wp = Wcls;
    bool wvalid = true;
    if (nrow < NCLS)              Wp = Wcls + (size_t)nrow * K + sg * 8;
    else if (nrow < NCLS + NREGR) Wp = Wreg + (size_t)(nrow - NCLS) * K + sg * 8;
    else                          wvalid = false;

    for (int k0 = 0; k0 < K; k0 += 32) {
        __syncthreads();
        s8v av = *(const s8v*)(Ahp + k0);
        s8v lv = *(const s8v*)(Alp + k0);
        float4 w0, w1;
        if (wvalid) {
            w0 = *(const float4*)(Wp + k0);
            w1 = *(const float4*)(Wp + k0 + 4);
        } else {
            w0 = make_float4(0.f, 0.f, 0.f, 0.f);
            w1 = w0;
        }
        float wf[8] = {w0.x, w0.y, w0.z, w0.w, w1.x, w1.y, w1.z, w1.w};
        s8v wh, wl;
#pragma unroll
        for (int j = 0; j < 8; ++j) {
            ushortt h = f2bf(wf[j]);
            wh[j] = (short)h;
            wl[j] = (short)f2bf(wf[j] - bf2f(h));
        }
        *(s8v*)&Ash[srow * PADK + sg * 8] = av;
        *(s8v*)&Asl[srow * PADK + sg * 8] = lv;
        *(s8v*)&Bsh[srow * PADK + sg * 8] = wh;
        *(s8v*)&Bsl[srow * PADK + sg * 8] = wl;
        __syncthreads();
        s8v ah[2], al[2], bh[2], bl[2];
#pragma unroll
        for (int s = 0; s < 2; ++s) {
            ah[s] = *(const s8v*)&Ash[(wm + s * 16 + l15) * PADK + quad * 8];
            al[s] = *(const s8v*)&Asl[(wm + s * 16 + l15) * PADK + quad * 8];
            bh[s] = *(const s8v*)&Bsh[(wn + s * 16 + l15) * PADK + quad * 8];
            bl[s] = *(const s8v*)&Bsl[(wn + s * 16 + l15) * PADK + quad * 8];
        }
#pragma unroll
        for (int sm = 0; sm < 2; ++sm)
#pragma unroll
            for (int sn = 0; sn < 2; ++sn) {
                acc[sm][sn] = __builtin_amdgcn_mfma_f32_16x16x32_bf16(al[sm], bl[sn], acc[sm][sn], 0, 0, 0);
                acc[sm][sn] = __builtin_amdgcn_mfma_f32_16x16x32_bf16(al[sm], bh[sn], acc[sm][sn], 0, 0, 0);
                acc[sm][sn] = __builtin_amdgcn_mfma_f32_16x16x32_bf16(ah[sm], bl[sn], acc[sm][sn], 0, 0, 0);
                acc[sm][sn] = __builtin_amdgcn_mfma_f32_16x16x32_bf16(ah[sm], bh[sn], acc[sm][sn], 0, 0, 0);
            }
    }
#pragma unroll
    for (int sm = 0; sm < 2; ++sm)
#pragma unroll
        for (int sn = 0; sn < 2; ++sn)
#pragma unroll
            for (int r = 0; r < 4; ++r) {
                int m = m0 + wm + sm * 16 + quad * 4 + r;
                int n = n0 + wn + sn * 16 + l15;
                float bb = (n < NCLS) ? bcls[n] : ((n < NCLS + NREGR) ? breg[n - NCLS] : 0.f);
                C[(size_t)m * N2PAD + n] = acc[sm][sn][r] + bb;
            }
}

// ---------------- assemble proposals + scores + start/end + xsel ----------------
__global__ __launch_bounds__(256) void k_assemble(const float* __restrict__ C2,
                                                  const float* __restrict__ AD,
                                                  float* __restrict__ outP,
                                                  float* __restrict__ outS,
                                                  float* __restrict__ startv,
                                                  float* __restrict__ endv,
                                                  float* __restrict__ xsel)
{
    int mb = blockIdx.x;                 // 0..1343
    int b = mb / NEDGE, e = mb - b * NEDGE;
    const float* c2 = C2 + (size_t)mb * N2PAD;
    int tid = threadIdx.x;
    for (int idx = tid; idx < NANG * NPREDD; idx += 256) {
        int a = idx / NPREDD, p = idx - a * NPREDD;
        int prop = e * NANG + a;
        float v;
        if (p < 2) v = c2[a * 2 + p];
        else {
            v = AD[prop * NPREDD + p];
            if (p >= 4) v += c2[NCLS + a * 73 + (p - 4)];
        }
        outP[((size_t)b * NPROPP + prop) * NPREDD + p] = v;
    }
    if (tid < NANG) {
        int a = tid, prop = e * NANG + a;
        float c0 = c2[2 * a], c1 = c2[2 * a + 1];
        float mx = fmaxf(c0, c1);
        float e0 = expf(c0 - mx), e1 = expf(c1 - mx);
        outS[b * NPROPP + prop] = e1 / (e0 + e1);
        float p2 = AD[prop * NPREDD + 2];
        float p4 = AD[prop * NPREDD + 4] + c2[NCLS + a * 73];
        float st = fminf(fmaxf(rintf(p2 * NSTRIPSF), 0.0f), NSTRIPSF);  // round half-to-even
        float en = fminf(fmaxf(st + p4 - 1.0f, 0.0f), NSTRIPSF);
        startv[b * 720 + prop] = st;
        endv[b * 720 + prop] = en;
        int ksi = (int)st;
        // bit-identical to outP[..][5+ksi]
        xsel[b * 720 + prop] = AD[prop * NPREDD + 5 + ksi] + c2[NCLS + a * 73 + ksi + 1];
    }
}

// ---------------- per-batch stable descending rank sort (parallel tiles) -------
__global__ __launch_bounds__(128) void k_sort(const float* __restrict__ scores,
                                              int* __restrict__ order)
{
    int b = blockIdx.x, tile = blockIdx.y, tid = threadIdx.x;
    __shared__ __align__(16) float s[720];
    for (int x = tid; x < 720; x += 128)
        s[x] = (x < NPROPP) ? scores[b * NPROPP + x] : -1e30f;
    __syncthreads();
    int i = tile * 128 + tid;
    if (i >= NPROPP) return;
    float si = s[i];
    int r = 0;
#pragma unroll 4
    for (int j4 = 0; j4 < 720; j4 += 4) {
        float4 v = *(const float4*)&s[j4];
        r += (v.x > si) || (v.x == si && (j4 + 0) < i);
        r += (v.y > si) || (v.y == si && (j4 + 1) < i);
        r += (v.z > si) || (v.z == si && (j4 + 2) < i);
        r += (v.w > si) || (v.w == si && (j4 + 3) < i);
    }
    order[b * 720 + r] = i;
}

// ---------------- suppression matrix, 64x64 tiles, xsel fast path ----------------
__global__ __launch_bounds__(256) void k_supmat(const float* __restrict__ outP,
                                                const float* __restrict__ startv,
                                                const float* __restrict__ endv,
                                                const float* __restrict__ xsel,
                                                const int* __restrict__ order,
                                                u64* __restrict__ sup)
{
    int jt = blockIdx.x, it = blockIdx.y, b = blockIdx.z;
    int i0 = it * 64, j0 = jt * 64;
    int tid = threadIdx.x;
    if (j0 + 63 < i0) {                  // strictly below diagonal: zero words
        if (tid < 64) {
            int il = i0 + tid;
            if (il < NPROPP) sup[((size_t)b * NPROPP + il) * 12 + jt] = 0ull;
        }
        return;
    }
    __shared__ float SI[64], EI[64], XI[64];
    __shared__ float SJ[64], EJ[64], XJ[64];
    __shared__ int   OI[64], OJ[64];
    if (tid < 128) {
        int side = tid >> 6, q = tid & 63;
        int pos = (side ? j0 : i0) + q;
        int o = (pos < NPROPP) ? order[b * 720 + pos] : -1;
        float st = (o >= 0) ? startv[b * 720 + o] : 0.f;
        float en = (o >= 0) ? endv[b * 720 + o] : -2.f;   // cnt<=-1 -> never suppress
        float xv = (o >= 0) ? xsel[b * 720 + o] : 0.f;
        if (!side) { SI[q] = st; EI[q] = en; XI[q] = xv; OI[q] = o; }
        else       { SJ[q] = st; EJ[q] = en; XJ[q] = xv; OJ[q] = o; }
    }
    __syncthreads();
    int lane = tid & 63, w = tid >> 6;
    int j = j0 + lane;
    float sj = SJ[lane], ej = EJ[lane], xj = XJ[lane];
    const float* basexs = outP + (size_t)b * NPROPP * NPREDD + 5;
#pragma unroll 1
    for (int rep = 0; rep < 16; ++rep) {
        int iloc = w * 16 + rep;
        int il = i0 + iloc;
        float si = SI[iloc], ei = EI[iloc];
        float s = fmaxf(si, sj), e = fminf(ei, ej);
        float cnt = e - s + 1.0f;
        bool sp = false;
        if (cnt > 0.f) {
            if (e < s) {
                sp = true;                               // empty range: dist = 0
            } else {
                int ks = (int)s, ke = (int)e;
                if (si == sj && ke == ks) {
                    sp = (fabsf(XI[iloc] - xj) / fmaxf(cnt, 1.0f)) < 15.0f;
                } else {                                  // rare general case
                    const float* xi  = basexs + (size_t)OI[iloc] * NPREDD;
                    const float* xjp = basexs + (size_t)OJ[lane] * NPREDD;
                    float sum = 0.f;
                    for (int k = ks; k <= ke; ++k)
                        sum += fabsf(xi[k] - xjp[k]);
                    sp = (sum / fmaxf(cnt, 1.0f)) < 15.0f;
                }
            }
        }
        bool valid = (il < NPROPP) && (j < NPROPP) && (j > il);
        u64 msk = __ballot(valid && sp);
        if (lane == 0 && il < NPROPP)
            sup[((size_t)b * NPROPP + il) * 12 + jt] = msk;
    }
}

// ---------------- NMS via Jacobi fixpoint (per batch, 256 threads) ----------------
// Greedy NMS keep is the UNIQUE fixpoint of keep[i] = !exists j<i: keep[j]&sup[j][i]
// (proof: induction on i). Iterate K <- valid & ~OR{row_j : K[j]} with full-width
// parallel sweeps until K is unchanged; K^t==K^{t-1} => fixpoint => exact greedy.
// Rows cached in VGPRs (3 rows/thread); per sweep: predicated register ORs +
// 12-word wave butterfly + 12 LDS atomicOr per wave. Sweeps ~ chain depth (~5-15).
__global__ __launch_bounds__(256) void k_scan(const u64* __restrict__ sup,
                                              const int* __restrict__ order,
                                              float* __restrict__ keep_out)
{
    int b = blockIdx.x, tid = threadIdx.x;
    int lane = tid & 63;
    __shared__ u64 K[12], NS[12];
    __shared__ int changed;
    const u64* base = sup + (size_t)b * NPROPP * 12;

    int r0 = tid, r1 = tid + 256, r2 = tid + 512;
    u64 row0[12], row1[12], row2[12];
#pragma unroll
    for (int t = 0; t < 12; ++t) {
        row0[t] = base[(size_t)r0 * 12 + t];                       // r0 < 714 always
        row1[t] = (r1 < NPROPP) ? base[(size_t)r1 * 12 + t] : 0ull;
        row2[t] = (r2 < NPROPP) ? base[(size_t)r2 * 12 + t] : 0ull;
    }
    if (tid < 12) {
        K[tid] = (tid < 11) ? ~0ull : ((1ull << (NPROPP - 704)) - 1ull);  // valid mask
        NS[tid] = 0ull;
    }
    __syncthreads();

    for (int sweep = 0; sweep < 720; ++sweep) {
        // phase A: accumulate OR of currently-kept rows (registers, predicated)
        u64 m0 = 0ull - ((K[r0 >> 6] >> (r0 & 63)) & 1ull);
        u64 m1 = (r1 < NPROPP) ? (0ull - ((K[r1 >> 6] >> (r1 & 63)) & 1ull)) : 0ull;
        u64 m2 = (r2 < NPROPP) ? (0ull - ((K[r2 >> 6] >> (r2 & 63)) & 1ull)) : 0ull;
        unsigned lo[12], hi[12];
#pragma unroll
        for (int t = 0; t < 12; ++t) {
            u64 a = (row0[t] & m0) | (row1[t] & m1) | (row2[t] & m2);
            lo[t] = (unsigned)a;
            hi[t] = (unsigned)(a >> 32);
        }
#pragma unroll
        for (int s = 1; s < 64; s <<= 1) {
#pragma unroll
            for (int t = 0; t < 12; ++t) {
                lo[t] |= __shfl_xor(lo[t], s, 64);
                hi[t] |= __shfl_xor(hi[t], s, 64);
            }
        }
        if (tid == 0) changed = 0;
        if (lane == 0) {
#pragma unroll
            for (int t = 0; t < 12; ++t)
                atomicOr(&NS[t], ((u64)hi[t] << 32) | (u64)lo[t]);
        }
        __syncthreads();
        // phase B: new keep, convergence check, reset NS
        if (tid < 12) {
            u64 valid = (tid < 11) ? ~0ull : ((1ull << (NPROPP - 704)) - 1ull);
            u64 nk = valid & ~NS[tid];
            if (nk != K[tid]) changed = 1;   // benign race: same value
            K[tid] = nk;
            NS[tid] = 0ull;
        }
        __syncthreads();
        if (!changed) break;
    }
    // scatter result through sort order
    if (r0 < NPROPP)
        keep_out[b * NPROPP + order[b * 720 + r0]] =
            ((K[r0 >> 6] >> (r0 & 63)) & 1ull) ? 1.f : 0.f;
    if (r1 < NPROPP)
        keep_out[b * NPROPP + order[b * 720 + r1]] =
            ((K[r1 >> 6] >> (r1 & 63)) & 1ull) ? 1.f : 0.f;
    if (r2 < NPROPP)
        keep_out[b * NPROPP + order[b * 720 + r2]] =
            ((K[r2 >> 6] >> (r2 & 63)) & 1ull) ? 1.f : 0.f;
}

extern "C" void kernel_launch(void* const* d_in, const int* in_sizes, int n_in,
                              void* d_out, int out_size, void* d_ws, size_t ws_size,
                              hipStream_t stream)
{
    const float* feat  = (const float*)d_in[0];
    const float* Wconv = (const float*)d_in[1];
    const float* bconv = (const float*)d_in[2];
    const float* Wcls  = (const float*)d_in[3];
    const float* bcls  = (const float*)d_in[4];
    const float* Wreg  = (const float*)d_in[5];
    const float* breg  = (const float*)d_in[6];
    const float* AD    = (const float*)d_in[8];   // anchors_anchor_dim (714,77)

    float* out  = (float*)d_out;
    float* outP = out;                                     // proposals 32*714*77
    float* outK = out + (size_t)NB * NPROPP * NPREDD;      // keep mask  32*714
    float* outS = outK + (size_t)NB * NPROPP;              // scores     32*714

    float* ws = (float*)d_ws;
    // [0, 688128) floats: A1hi/A1lo bf16 (dead after gemm1) -> NMS scratch later
    ushortt* A1hi = (ushortt*)ws;                          // 688128 bf16
    ushortt* A1lo = (ushortt*)(ws + 344064);               // 688128 bf16
    ushortt* A2hi = (ushortt*)(ws + 688128);               // 1344*1024 bf16
    ushortt* A2lo = (ushortt*)(ws + 1376256);              // 1344*1024 bf16
    float*   C2   = ws + 2064384;                          // 1344*1280 fp32, ends 3784704
    // NMS scratch overlays dead A1 region:
    float* startv = ws;                                    // 32*720 floats
    float* endv   = ws + 23040;                            // 32*720 floats
    int*   order  = (int*)(ws + 46080);                    // 32*720 ints
    u64*   sup    = (u64*)(ws + 69120);                    // 32*714*12 u64, ends @617472
    float* xsel   = ws + 617472;                           // 32*720 floats, ends @640512

    k_gather_split<<<dim3(2688),       dim3(256), 0, stream>>>(feat, A1hi, A1lo);
    k_gemm1m      <<<dim3(16, 21),     dim3(256), 0, stream>>>(A1hi, A1lo, Wconv, bconv, A2hi, A2lo);
    k_gemm2m      <<<dim3(20, 21),     dim3(256), 0, stream>>>(A2hi, A2lo, Wcls, bcls, Wreg, breg, C2);
    k_assemble    <<<dim3(MTOT),       dim3(256), 0, stream>>>(C2, AD, outP, outS, startv, endv, xsel);
    k_sort        <<<dim3(NB, 6),      dim3(128), 0, stream>>>(outS, order);
    k_supmat      <<<dim3(12, 12, NB), dim3(256), 0, stream>>>(outP, startv, endv, xsel, order, sup);
    k_scan        <<<dim3(NB),         dim3(256), 0, stream>>>(sup, order, outK);
}